// Round 5
// baseline (2046.836 us; speedup 1.0000x reference)
//
#include <hip/hip_runtime.h>

#define T_STEPS 100
#define NTRAJ   8192
#define MBLK    8      // trajectories per block (rows 8-15 of MFMA tile are waste)
#define ROWS    16     // MFMA/LDS tile rows

typedef __attribute__((ext_vector_type(8))) _Float16 f16x8;
typedef __attribute__((ext_vector_type(4))) float    f32x4;

#define MFMA16(a, b, c) __builtin_amdgcn_mfma_f32_16x16x32_f16((a), (b), (c), 0, 0, 0)

// XOR swizzle on element index within a row (2B elems; XOR elem bits 3..5)
#define SWZ(row, col) ((col) ^ (((row) & 7) << 3))

__device__ __forceinline__ float fast_tanh(float x) {
    float e = __expf(2.f * x);
    return 1.f - 2.f * __builtin_amdgcn_rcpf(1.f + e);
}
__device__ __forceinline__ float fast_sigmoid(float x) {
    float e = __expf(-x);
    return __builtin_amdgcn_rcpf(1.f + e);
}

// ---------------------------------------------------------------------------
// Weight packing (unchanged): B-fragment tile order, 144 tiles of 512 f16.
// ---------------------------------------------------------------------------
__global__ void pack_kernel(const float* __restrict__ Wo1, const float* __restrict__ Wo2,
                            const float* __restrict__ Wz1, const float* __restrict__ Wz2,
                            const float* __restrict__ Wr1, const float* __restrict__ Wr2,
                            const float* __restrict__ Wh1, const float* __restrict__ Wh2,
                            _Float16* __restrict__ P)
{
    int idx = blockIdx.x * 256 + threadIdx.x;
    if (idx >= 144 * 512) return;
    int tile = idx >> 9;
    int r    = idx & 511;
    int lane = r >> 3, j = r & 7;
    int krel = ((lane >> 4) << 3) + j;   // 0..31
    int c16  = lane & 15;
    float val = 0.f;

    if (tile < 14) {                       // ODE L1
        int t = tile, nt = t >> 1, kt = t & 1;
        int k = kt * 32 + krel, n = nt * 16 + c16;
        if (k < 64 && n < 100) val = Wo1[k * 100 + n];
    } else if (tile < 30) {                // ODE L2
        int t = tile - 14, nt = t >> 2, kt = t & 3;
        int k = kt * 32 + krel, n = nt * 16 + c16;
        if (k < 100) val = Wo2[k * 64 + n];
    } else if (tile < 75) {                // ZR L1
        int t = tile - 30, nt = t / 3, kt = t % 3;
        int k = kt * 32 + krel;            // K = 96 exact
        if (nt < 7)      { int n = nt * 16 + c16;        if (n < 100) val = Wz1[k * 100 + n]; }
        else if (nt >= 8){ int n = (nt - 8) * 16 + c16;  if (n < 100) val = Wr1[k * 100 + n]; }
    } else if (tile < 107) {               // ZR L2
        int t = tile - 75, gate = t >> 4, rem = t & 15, nt = rem >> 2, kt = rem & 3;
        int k = kt * 32 + krel, n = nt * 16 + c16;
        const float* W = gate ? Wr2 : Wz2;
        if (k < 100) val = W[k * 64 + n];
    } else if (tile < 128) {               // H L1
        int t = tile - 107, nt = t / 3, kt = t % 3;
        int k = kt * 32 + krel, n = nt * 16 + c16;
        if (n < 100) val = Wh1[k * 100 + n];
    } else {                               // H L2
        int t = tile - 128, nt = t >> 2, kt = t & 3;
        int k = kt * 32 + krel, n = nt * 16 + c16;
        if (k < 100) val = Wh2[k * 64 + n];
    }
    P[idx] = (_Float16)val;
}

__device__ __forceinline__ f16x8 ldsA(const _Float16* buf, int stride, int row, int kcol) {
    return *(const f16x8*)(buf + row * stride + SWZ(row, kcol));
}

// ---------------------------------------------------------------------------
// Main kernel. Block = 8 trajectories (rows 0-7 of a 16-row MFMA tile),
// 256 threads = 4 waves splitting N-tiles. Grid = 1024 -> 4 blocks/CU for
// latency hiding (round-1 was grid-capped at 2). Rows 8-15 carry finite
// garbage and are never stored. State y/yode/zg in registers (wave wv owns
// columns wv*16..wv*16+15). x prefetched one full step ahead.
// ---------------------------------------------------------------------------
__global__ __launch_bounds__(256, 4) void odernn_kernel(
    const float* __restrict__ data, const float* __restrict__ ts,
    const float* __restrict__ prior,
    const float* __restrict__ bo1, const float* __restrict__ bo2,
    const float* __restrict__ bz1, const float* __restrict__ bz2,
    const float* __restrict__ br1, const float* __restrict__ br2,
    const float* __restrict__ bh1, const float* __restrict__ bh2,
    const _Float16* __restrict__ P, float* __restrict__ out)
{
    __shared__ __align__(16) _Float16 sYb[ROWS * 64];   // y (f16), G1 A input
    __shared__ __align__(16) _Float16 sYX[ROWS * 128];  // [yode | x]
    __shared__ __align__(16) _Float16 sRX[ROWS * 128];  // [rg*yode | x]
    __shared__ __align__(16) _Float16 sH1[ROWS * 128];  // hidden (ODE L1 / H L1)
    __shared__ __align__(16) _Float16 sZR[ROWS * 256];  // [z-hidden(112)+pad | r-hidden(112)+pad]

    const int tid  = threadIdx.x;
    const int lane = tid & 63;
    const int wv   = tid >> 6;            // 0..3
    const int c16  = lane & 15;
    const int g4   = lane >> 4;
    const int m0   = blockIdx.x * MBLK;
    const int colw = wv * 16 + c16;       // this lane's "own" column
    const f16x8* Pt = (const f16x8*)P;

    // ---- preload biases (step-invariant per lane) ----
    float b_o1[2], b_h1[2], b_zr[4];
    {
        int c0 = wv * 16 + c16, c1 = (wv + 4) * 16 + c16;
        b_o1[0] = (c0 < 100) ? bo1[c0] : 0.f;
        b_h1[0] = (c0 < 100) ? bh1[c0] : 0.f;
        b_o1[1] = (wv + 4 < 7 && c1 < 100) ? bo1[c1] : 0.f;
        b_h1[1] = (wv + 4 < 7 && c1 < 100) ? bh1[c1] : 0.f;
        #pragma unroll
        for (int q = 0; q < 4; ++q) {
            int i = wv + 4 * q;
            float v = 0.f;
            if (i < 14) {
                int bt = (i < 7) ? i : i + 1;
                int col = bt * 16 + c16;
                int bc = (i < 7) ? col : col - 128;
                if (bc < 100) v = (i < 7) ? bz1[bc] : br1[bc];
            }
            b_zr[q] = v;
        }
    }
    const float b_o2 = bo2[colw], b_z2 = bz2[colw], b_r2 = br2[colw], b_h2 = bh2[colw];

    // ---- preload B-fragments for the short dependent phases G2/G6 ----
    f16x8 Bo2[4], Bh2[4];
    #pragma unroll
    for (int kt = 0; kt < 4; ++kt) {
        Bo2[kt] = Pt[(14 + wv * 4 + kt) * 64 + lane];
        Bh2[kt] = Pt[(128 + wv * 4 + kt) * 64 + lane];
    }

    // ---- init: y state in regs (rows>=8 clamped; finite garbage), sYb, pads ----
    float y[4];
    #pragma unroll
    for (int r = 0; r < 4; ++r) {
        int row = g4 * 4 + r;
        int gr = m0 + row; if (gr > NTRAJ - 1) gr = NTRAJ - 1;
        y[r] = prior[(size_t)gr * 64 + colw];
        sYb[row * 64 + SWZ(row, colw)] = (_Float16)y[r];
    }
    {   // sH1 pad cols 112..127, all 16 rows (256 elems, 1/thread)
        int row = tid >> 4, col = 112 + (tid & 15);
        sH1[row * 128 + SWZ(row, col)] = (_Float16)0.f;
    }
    for (int i = tid; i < ROWS * 32; i += 256) {  // sZR pads (both halves)
        int row = i >> 5, cc = i & 31;
        int col = (cc < 16) ? (112 + cc) : (224 + cc);
        sZR[row * 256 + SWZ(row, col)] = (_Float16)0.f;
    }
    {   // x-region rows 8..15 of sYX/sRX: never staged, zero once (256 elems)
        int row = 8 + (tid >> 5), cc = tid & 31;
        int sw = row * 128 + SWZ(row, 64 + cc);
        sYX[sw] = (_Float16)0.f;
        sRX[sw] = (_Float16)0.f;
    }
    __syncthreads();

    const float t0 = ts[0], t1 = ts[1];

    // x element owned by this thread: row = tid>>5 (0..7), c = tid&31; t = s+1
    const int xrow = tid >> 5, xc = tid & 31;
    const float* xptr = data + (size_t)(m0 + xrow) * (T_STEPS * 32) + 32 + xc;
    const int xsw = xrow * 128 + SWZ(xrow, 64 + xc);
    float xv_cur = *xptr;   // x for step 0

    #pragma unroll 1
    for (int s = 0; s < T_STEPS - 1; ++s) {
        const float dt = (s == 0) ? (t1 - t0) : (ts[s - 1] - ts[s]);

        // prefetch next step's x (covered by the whole step)
        xptr += 32;
        float xv_next = (s < T_STEPS - 2) ? *xptr : 0.f;

        // ---- G1: H1 = tanh(y @ Wo1 + bo1)  [16x64]@[64x112] ----
        {
            f16x8 a0 = ldsA(sYb, 64, c16, (g4 << 3));
            f16x8 a1 = ldsA(sYb, 64, c16, 32 + (g4 << 3));
            #pragma unroll
            for (int t = 0; t < 2; ++t) {
                int nt = wv + 4 * t;
                if (nt < 7) {
                    f32x4 z4 = {0.f, 0.f, 0.f, 0.f};
                    f32x4 acc0 = MFMA16(a0, Pt[(nt * 2 + 0) * 64 + lane], z4);
                    f32x4 acc1 = MFMA16(a1, Pt[(nt * 2 + 1) * 64 + lane], z4);
                    int col = nt * 16 + c16;
                    #pragma unroll
                    for (int r = 0; r < 4; ++r) {
                        int row = g4 * 4 + r;
                        sH1[row * 128 + SWZ(row, col)] = (_Float16)fast_tanh(acc0[r] + acc1[r] + b_o1[t]);
                    }
                }
            }
        }
        // ---- stage current x into both concat buffers (1 elem/thread) ----
        {
            _Float16 xh = (_Float16)xv_cur;
            sYX[xsw] = xh; sRX[xsw] = xh;
        }
        __syncthreads();

        // ---- G2: yode = y + dt*(H1 @ Wo2 + bo2); yode in regs ----
        float yo[4];
        {
            f32x4 z4 = {0.f, 0.f, 0.f, 0.f};
            f32x4 acc0 = z4, acc1 = z4;
            acc0 = MFMA16(ldsA(sH1, 128, c16, 0 * 32 + (g4 << 3)), Bo2[0], acc0);
            acc1 = MFMA16(ldsA(sH1, 128, c16, 1 * 32 + (g4 << 3)), Bo2[1], acc1);
            acc0 = MFMA16(ldsA(sH1, 128, c16, 2 * 32 + (g4 << 3)), Bo2[2], acc0);
            acc1 = MFMA16(ldsA(sH1, 128, c16, 3 * 32 + (g4 << 3)), Bo2[3], acc1);
            #pragma unroll
            for (int r = 0; r < 4; ++r) {
                int row = g4 * 4 + r;
                yo[r] = y[r] + dt * (acc0[r] + acc1[r] + b_o2);
                sYX[row * 128 + SWZ(row, colw)] = (_Float16)yo[r];
            }
        }
        __syncthreads();

        // ---- G3: zr-hidden = tanh([yode|x] @ W{z,r}1 + b)  [16x96]@[96x224] ----
        {
            f16x8 a0 = ldsA(sYX, 128, c16, 0 * 32 + (g4 << 3));
            f16x8 a1 = ldsA(sYX, 128, c16, 1 * 32 + (g4 << 3));
            f16x8 a2 = ldsA(sYX, 128, c16, 2 * 32 + (g4 << 3));
            #pragma unroll
            for (int q = 0; q < 4; ++q) {
                int i = wv + 4 * q;
                if (i < 14) {
                    int bt = (i < 7) ? i : i + 1;
                    f32x4 z4 = {0.f, 0.f, 0.f, 0.f};
                    f32x4 acc0 = MFMA16(a0, Pt[(30 + bt * 3 + 0) * 64 + lane], z4);
                    f32x4 acc1 = MFMA16(a1, Pt[(30 + bt * 3 + 1) * 64 + lane], z4);
                    acc0 = MFMA16(a2, Pt[(30 + bt * 3 + 2) * 64 + lane], acc0);
                    int col = bt * 16 + c16;
                    #pragma unroll
                    for (int r = 0; r < 4; ++r) {
                        int row = g4 * 4 + r;
                        sZR[row * 256 + SWZ(row, col)] = (_Float16)fast_tanh(acc0[r] + acc1[r] + b_zr[q]);
                    }
                }
            }
        }
        __syncthreads();

        // ---- G4: wave wv owns tile nt=wv for BOTH gates; zg regs, rg*yode->sRX ----
        float zg[4];
        {
            f32x4 z4 = {0.f, 0.f, 0.f, 0.f};
            f32x4 accz0 = z4, accz1 = z4, accr0 = z4, accr1 = z4;
            accz0 = MFMA16(ldsA(sZR, 256, c16, 0 * 32 + (g4 << 3)), Pt[(75 + wv * 4 + 0) * 64 + lane], accz0);
            accr0 = MFMA16(ldsA(sZR, 256, c16, 128 + 0 * 32 + (g4 << 3)), Pt[(91 + wv * 4 + 0) * 64 + lane], accr0);
            accz1 = MFMA16(ldsA(sZR, 256, c16, 1 * 32 + (g4 << 3)), Pt[(75 + wv * 4 + 1) * 64 + lane], accz1);
            accr1 = MFMA16(ldsA(sZR, 256, c16, 128 + 1 * 32 + (g4 << 3)), Pt[(91 + wv * 4 + 1) * 64 + lane], accr1);
            accz0 = MFMA16(ldsA(sZR, 256, c16, 2 * 32 + (g4 << 3)), Pt[(75 + wv * 4 + 2) * 64 + lane], accz0);
            accr0 = MFMA16(ldsA(sZR, 256, c16, 128 + 2 * 32 + (g4 << 3)), Pt[(91 + wv * 4 + 2) * 64 + lane], accr0);
            accz1 = MFMA16(ldsA(sZR, 256, c16, 3 * 32 + (g4 << 3)), Pt[(75 + wv * 4 + 3) * 64 + lane], accz1);
            accr1 = MFMA16(ldsA(sZR, 256, c16, 128 + 3 * 32 + (g4 << 3)), Pt[(91 + wv * 4 + 3) * 64 + lane], accr1);
            #pragma unroll
            for (int r = 0; r < 4; ++r) {
                int row = g4 * 4 + r;
                zg[r] = fast_sigmoid(accz0[r] + accz1[r] + b_z2);
                float rv = fast_sigmoid(accr0[r] + accr1[r] + b_r2) * yo[r];
                sRX[row * 128 + SWZ(row, colw)] = (_Float16)rv;
            }
        }
        __syncthreads();

        // ---- G5: H1 = tanh([rg*yode|x] @ Wh1 + bh1) ----
        {
            f16x8 a0 = ldsA(sRX, 128, c16, 0 * 32 + (g4 << 3));
            f16x8 a1 = ldsA(sRX, 128, c16, 1 * 32 + (g4 << 3));
            f16x8 a2 = ldsA(sRX, 128, c16, 2 * 32 + (g4 << 3));
            #pragma unroll
            for (int t = 0; t < 2; ++t) {
                int nt = wv + 4 * t;
                if (nt < 7) {
                    f32x4 z4 = {0.f, 0.f, 0.f, 0.f};
                    f32x4 acc0 = MFMA16(a0, Pt[(107 + nt * 3 + 0) * 64 + lane], z4);
                    f32x4 acc1 = MFMA16(a1, Pt[(107 + nt * 3 + 1) * 64 + lane], z4);
                    acc0 = MFMA16(a2, Pt[(107 + nt * 3 + 2) * 64 + lane], acc0);
                    int col = nt * 16 + c16;
                    #pragma unroll
                    for (int r = 0; r < 4; ++r) {
                        int row = g4 * 4 + r;
                        sH1[row * 128 + SWZ(row, col)] = (_Float16)fast_tanh(acc0[r] + acc1[r] + b_h1[t]);
                    }
                }
            }
        }
        __syncthreads();

        // ---- G6: h = tanh(H1 @ Wh2 + bh2); y = (1-z)*h + z*yode (all regs) ----
        {
            f32x4 z4 = {0.f, 0.f, 0.f, 0.f};
            f32x4 acc0 = z4, acc1 = z4;
            acc0 = MFMA16(ldsA(sH1, 128, c16, 0 * 32 + (g4 << 3)), Bh2[0], acc0);
            acc1 = MFMA16(ldsA(sH1, 128, c16, 1 * 32 + (g4 << 3)), Bh2[1], acc1);
            acc0 = MFMA16(ldsA(sH1, 128, c16, 2 * 32 + (g4 << 3)), Bh2[2], acc0);
            acc1 = MFMA16(ldsA(sH1, 128, c16, 3 * 32 + (g4 << 3)), Bh2[3], acc1);
            #pragma unroll
            for (int r = 0; r < 4; ++r) {
                int row = g4 * 4 + r;
                float h = fast_tanh(acc0[r] + acc1[r] + b_h2);
                y[r] = (1.f - zg[r]) * h + zg[r] * yo[r];
                sYb[row * 64 + SWZ(row, colw)] = (_Float16)y[r];
            }
        }
        __syncthreads();

        xv_cur = xv_next;
    }

    // only rows 0..7 are real trajectories
    if (g4 < 2) {
        #pragma unroll
        for (int r = 0; r < 4; ++r) {
            int row = g4 * 4 + r;
            out[(size_t)(m0 + row) * 64 + colw] = y[r];
        }
    }
}

extern "C" void kernel_launch(void* const* d_in, const int* in_sizes, int n_in,
                              void* d_out, int out_size, void* d_ws, size_t ws_size,
                              hipStream_t stream) {
    const float* data = (const float*)d_in[0];
    const float* ts   = (const float*)d_in[1];
    const float* prior= (const float*)d_in[2];
    const float* Wo1 = (const float*)d_in[3];  const float* bo1 = (const float*)d_in[4];
    const float* Wo2 = (const float*)d_in[5];  const float* bo2 = (const float*)d_in[6];
    const float* Wz1 = (const float*)d_in[7];  const float* bz1 = (const float*)d_in[8];
    const float* Wz2 = (const float*)d_in[9];  const float* bz2 = (const float*)d_in[10];
    const float* Wr1 = (const float*)d_in[11]; const float* br1 = (const float*)d_in[12];
    const float* Wr2 = (const float*)d_in[13]; const float* br2 = (const float*)d_in[14];
    const float* Wh1 = (const float*)d_in[15]; const float* bh1 = (const float*)d_in[16];
    const float* Wh2 = (const float*)d_in[17]; const float* bh2 = (const float*)d_in[18];
    _Float16* P = (_Float16*)d_ws;
    float* out = (float*)d_out;

    hipLaunchKernelGGL(pack_kernel, dim3((144 * 512 + 255) / 256), dim3(256), 0, stream,
                       Wo1, Wo2, Wz1, Wz2, Wr1, Wr2, Wh1, Wh2, P);
    hipLaunchKernelGGL(odernn_kernel, dim3(NTRAJ / MBLK), dim3(256), 0, stream,
                       data, ts, prior, bo1, bo2, bz1, bz2, br1, br2, bh1, bh2, P, out);
}

// Round 6
// 712.664 us; speedup vs baseline: 2.8721x; 2.8721x over previous
//
#include <hip/hip_runtime.h>

#define T_STEPS 100
#define NTRAJ   8192
#define MBLK    8      // trajectories per block (rows 8-15 of MFMA tile are waste)
#define ROWS    16     // MFMA/LDS tile rows

typedef __attribute__((ext_vector_type(8))) _Float16 f16x8;
typedef __attribute__((ext_vector_type(4))) float    f32x4;

#define MFMA16(a, b, c) __builtin_amdgcn_mfma_f32_16x16x32_f16((a), (b), (c), 0, 0, 0)

// XOR swizzle on element index within a row (2B elems; XOR elem bits 3..5)
#define SWZ(row, col) ((col) ^ (((row) & 7) << 3))

__device__ __forceinline__ float fast_tanh(float x) {
    float e = __expf(2.f * x);
    return 1.f - 2.f * __builtin_amdgcn_rcpf(1.f + e);
}
__device__ __forceinline__ float fast_sigmoid(float x) {
    float e = __expf(-x);
    return __builtin_amdgcn_rcpf(1.f + e);
}

// ---------------------------------------------------------------------------
// Weight packing (unchanged): B-fragment tile order, 144 tiles of 512 f16.
// ---------------------------------------------------------------------------
__global__ void pack_kernel(const float* __restrict__ Wo1, const float* __restrict__ Wo2,
                            const float* __restrict__ Wz1, const float* __restrict__ Wz2,
                            const float* __restrict__ Wr1, const float* __restrict__ Wr2,
                            const float* __restrict__ Wh1, const float* __restrict__ Wh2,
                            _Float16* __restrict__ P)
{
    int idx = blockIdx.x * 256 + threadIdx.x;
    if (idx >= 144 * 512) return;
    int tile = idx >> 9;
    int r    = idx & 511;
    int lane = r >> 3, j = r & 7;
    int krel = ((lane >> 4) << 3) + j;   // 0..31
    int c16  = lane & 15;
    float val = 0.f;

    if (tile < 14) {                       // ODE L1
        int t = tile, nt = t >> 1, kt = t & 1;
        int k = kt * 32 + krel, n = nt * 16 + c16;
        if (k < 64 && n < 100) val = Wo1[k * 100 + n];
    } else if (tile < 30) {                // ODE L2
        int t = tile - 14, nt = t >> 2, kt = t & 3;
        int k = kt * 32 + krel, n = nt * 16 + c16;
        if (k < 100) val = Wo2[k * 64 + n];
    } else if (tile < 75) {                // ZR L1
        int t = tile - 30, nt = t / 3, kt = t % 3;
        int k = kt * 32 + krel;            // K = 96 exact
        if (nt < 7)      { int n = nt * 16 + c16;        if (n < 100) val = Wz1[k * 100 + n]; }
        else if (nt >= 8){ int n = (nt - 8) * 16 + c16;  if (n < 100) val = Wr1[k * 100 + n]; }
    } else if (tile < 107) {               // ZR L2
        int t = tile - 75, gate = t >> 4, rem = t & 15, nt = rem >> 2, kt = rem & 3;
        int k = kt * 32 + krel, n = nt * 16 + c16;
        const float* W = gate ? Wr2 : Wz2;
        if (k < 100) val = W[k * 64 + n];
    } else if (tile < 128) {               // H L1
        int t = tile - 107, nt = t / 3, kt = t % 3;
        int k = kt * 32 + krel, n = nt * 16 + c16;
        if (n < 100) val = Wh1[k * 100 + n];
    } else {                               // H L2
        int t = tile - 128, nt = t >> 2, kt = t & 3;
        int k = kt * 32 + krel, n = nt * 16 + c16;
        if (k < 100) val = Wh2[k * 64 + n];
    }
    P[idx] = (_Float16)val;
}

__device__ __forceinline__ f16x8 ldsA(const _Float16* buf, int stride, int row, int kcol) {
    return *(const f16x8*)(buf + row * stride + SWZ(row, kcol));
}

// ---------------------------------------------------------------------------
// Main kernel. Block = 8 trajectories (rows 0-7 of a 16-row MFMA tile),
// 256 threads = 4 waves. Grid = 1024 -> 4 blocks/CU *by hardware scheduling*:
// launch_bounds stays (256,2) — the 256-VGPR cap that never spills (rounds
// 2/4 lesson: any cap >=4 waves/EU forces a 64-reg split and massive spill).
// Natural allocation ~116 <= 128 lets HW fit 4 waves/SIMD anyway.
// ---------------------------------------------------------------------------
__global__ __launch_bounds__(256, 2) void odernn_kernel(
    const float* __restrict__ data, const float* __restrict__ ts,
    const float* __restrict__ prior,
    const float* __restrict__ bo1, const float* __restrict__ bo2,
    const float* __restrict__ bz1, const float* __restrict__ bz2,
    const float* __restrict__ br1, const float* __restrict__ br2,
    const float* __restrict__ bh1, const float* __restrict__ bh2,
    const _Float16* __restrict__ P, float* __restrict__ out)
{
    __shared__ __align__(16) _Float16 sYb[ROWS * 64];   // y (f16), G1 A input
    __shared__ __align__(16) _Float16 sYX[ROWS * 128];  // [yode | x]
    __shared__ __align__(16) _Float16 sRX[ROWS * 128];  // [rg*yode | x]
    __shared__ __align__(16) _Float16 sH1[ROWS * 128];  // hidden (ODE L1 / H L1)
    __shared__ __align__(16) _Float16 sZR[ROWS * 256];  // [z-hidden(112)+pad | r-hidden(112)+pad]

    const int tid  = threadIdx.x;
    const int lane = tid & 63;
    const int wv   = tid >> 6;            // 0..3
    const int c16  = lane & 15;
    const int g4   = lane >> 4;
    const int m0   = blockIdx.x * MBLK;
    const int colw = wv * 16 + c16;       // this lane's "own" column
    const f16x8* Pt = (const f16x8*)P;

    // ---- preload biases (step-invariant per lane) ----
    float b_o1[2], b_h1[2], b_zr[4];
    {
        int c0 = wv * 16 + c16, c1 = (wv + 4) * 16 + c16;
        b_o1[0] = (c0 < 100) ? bo1[c0] : 0.f;
        b_h1[0] = (c0 < 100) ? bh1[c0] : 0.f;
        b_o1[1] = (wv + 4 < 7 && c1 < 100) ? bo1[c1] : 0.f;
        b_h1[1] = (wv + 4 < 7 && c1 < 100) ? bh1[c1] : 0.f;
        #pragma unroll
        for (int q = 0; q < 4; ++q) {
            int i = wv + 4 * q;
            float v = 0.f;
            if (i < 14) {
                int bt = (i < 7) ? i : i + 1;
                int col = bt * 16 + c16;
                int bc = (i < 7) ? col : col - 128;
                if (bc < 100) v = (i < 7) ? bz1[bc] : br1[bc];
            }
            b_zr[q] = v;
        }
    }
    const float b_o2 = bo2[colw], b_z2 = bz2[colw], b_r2 = br2[colw], b_h2 = bh2[colw];

    // ---- preload B-fragments for the short dependent phases G2/G6 ----
    f16x8 Bo2[4], Bh2[4];
    #pragma unroll
    for (int kt = 0; kt < 4; ++kt) {
        Bo2[kt] = Pt[(14 + wv * 4 + kt) * 64 + lane];
        Bh2[kt] = Pt[(128 + wv * 4 + kt) * 64 + lane];
    }

    // ---- init: y state in regs (rows>=8 clamped; finite garbage), sYb, pads ----
    float y[4];
    #pragma unroll
    for (int r = 0; r < 4; ++r) {
        int row = g4 * 4 + r;
        int gr = m0 + row; if (gr > NTRAJ - 1) gr = NTRAJ - 1;
        y[r] = prior[(size_t)gr * 64 + colw];
        sYb[row * 64 + SWZ(row, colw)] = (_Float16)y[r];
    }
    {   // sH1 pad cols 112..127, all 16 rows (256 elems, 1/thread)
        int row = tid >> 4, col = 112 + (tid & 15);
        sH1[row * 128 + SWZ(row, col)] = (_Float16)0.f;
    }
    for (int i = tid; i < ROWS * 32; i += 256) {  // sZR pads (both halves)
        int row = i >> 5, cc = i & 31;
        int col = (cc < 16) ? (112 + cc) : (224 + cc);
        sZR[row * 256 + SWZ(row, col)] = (_Float16)0.f;
    }
    {   // x-region rows 8..15 of sYX/sRX: never staged, zero once (256 elems)
        int row = 8 + (tid >> 5), cc = tid & 31;
        int sw = row * 128 + SWZ(row, 64 + cc);
        sYX[sw] = (_Float16)0.f;
        sRX[sw] = (_Float16)0.f;
    }
    __syncthreads();

    const float t0 = ts[0], t1 = ts[1];

    // x element owned by this thread: row = tid>>5 (0..7), c = tid&31; t = s+1
    const int xrow = tid >> 5, xc = tid & 31;
    const float* xptr = data + (size_t)(m0 + xrow) * (T_STEPS * 32) + 32 + xc;
    const int xsw = xrow * 128 + SWZ(xrow, 64 + xc);
    float xv_cur = *xptr;   // x for step 0

    #pragma unroll 1
    for (int s = 0; s < T_STEPS - 1; ++s) {
        const float dt = (s == 0) ? (t1 - t0) : (ts[s - 1] - ts[s]);

        // prefetch next step's x (covered by the whole step)
        xptr += 32;
        float xv_next = (s < T_STEPS - 2) ? *xptr : 0.f;

        // ---- G1: H1 = tanh(y @ Wo1 + bo1)  [16x64]@[64x112] ----
        {
            f16x8 a0 = ldsA(sYb, 64, c16, (g4 << 3));
            f16x8 a1 = ldsA(sYb, 64, c16, 32 + (g4 << 3));
            #pragma unroll
            for (int t = 0; t < 2; ++t) {
                int nt = wv + 4 * t;
                if (nt < 7) {
                    f32x4 z4 = {0.f, 0.f, 0.f, 0.f};
                    f32x4 acc0 = MFMA16(a0, Pt[(nt * 2 + 0) * 64 + lane], z4);
                    f32x4 acc1 = MFMA16(a1, Pt[(nt * 2 + 1) * 64 + lane], z4);
                    int col = nt * 16 + c16;
                    #pragma unroll
                    for (int r = 0; r < 4; ++r) {
                        int row = g4 * 4 + r;
                        sH1[row * 128 + SWZ(row, col)] = (_Float16)fast_tanh(acc0[r] + acc1[r] + b_o1[t]);
                    }
                }
            }
        }
        // ---- stage current x into both concat buffers (1 elem/thread) ----
        {
            _Float16 xh = (_Float16)xv_cur;
            sYX[xsw] = xh; sRX[xsw] = xh;
        }
        __syncthreads();

        // ---- G2: yode = y + dt*(H1 @ Wo2 + bo2); yode in regs ----
        float yo[4];
        {
            f32x4 z4 = {0.f, 0.f, 0.f, 0.f};
            f32x4 acc0 = z4, acc1 = z4;
            acc0 = MFMA16(ldsA(sH1, 128, c16, 0 * 32 + (g4 << 3)), Bo2[0], acc0);
            acc1 = MFMA16(ldsA(sH1, 128, c16, 1 * 32 + (g4 << 3)), Bo2[1], acc1);
            acc0 = MFMA16(ldsA(sH1, 128, c16, 2 * 32 + (g4 << 3)), Bo2[2], acc0);
            acc1 = MFMA16(ldsA(sH1, 128, c16, 3 * 32 + (g4 << 3)), Bo2[3], acc1);
            #pragma unroll
            for (int r = 0; r < 4; ++r) {
                int row = g4 * 4 + r;
                yo[r] = y[r] + dt * (acc0[r] + acc1[r] + b_o2);
                sYX[row * 128 + SWZ(row, colw)] = (_Float16)yo[r];
            }
        }
        __syncthreads();

        // ---- G3: zr-hidden = tanh([yode|x] @ W{z,r}1 + b)  [16x96]@[96x224] ----
        {
            f16x8 a0 = ldsA(sYX, 128, c16, 0 * 32 + (g4 << 3));
            f16x8 a1 = ldsA(sYX, 128, c16, 1 * 32 + (g4 << 3));
            f16x8 a2 = ldsA(sYX, 128, c16, 2 * 32 + (g4 << 3));
            #pragma unroll
            for (int q = 0; q < 4; ++q) {
                int i = wv + 4 * q;
                if (i < 14) {
                    int bt = (i < 7) ? i : i + 1;
                    f32x4 z4 = {0.f, 0.f, 0.f, 0.f};
                    f32x4 acc0 = MFMA16(a0, Pt[(30 + bt * 3 + 0) * 64 + lane], z4);
                    f32x4 acc1 = MFMA16(a1, Pt[(30 + bt * 3 + 1) * 64 + lane], z4);
                    acc0 = MFMA16(a2, Pt[(30 + bt * 3 + 2) * 64 + lane], acc0);
                    int col = bt * 16 + c16;
                    #pragma unroll
                    for (int r = 0; r < 4; ++r) {
                        int row = g4 * 4 + r;
                        sZR[row * 256 + SWZ(row, col)] = (_Float16)fast_tanh(acc0[r] + acc1[r] + b_zr[q]);
                    }
                }
            }
        }
        __syncthreads();

        // ---- G4: wave wv owns tile nt=wv for BOTH gates; zg regs, rg*yode->sRX ----
        float zg[4];
        {
            f32x4 z4 = {0.f, 0.f, 0.f, 0.f};
            f32x4 accz0 = z4, accz1 = z4, accr0 = z4, accr1 = z4;
            accz0 = MFMA16(ldsA(sZR, 256, c16, 0 * 32 + (g4 << 3)), Pt[(75 + wv * 4 + 0) * 64 + lane], accz0);
            accr0 = MFMA16(ldsA(sZR, 256, c16, 128 + 0 * 32 + (g4 << 3)), Pt[(91 + wv * 4 + 0) * 64 + lane], accr0);
            accz1 = MFMA16(ldsA(sZR, 256, c16, 1 * 32 + (g4 << 3)), Pt[(75 + wv * 4 + 1) * 64 + lane], accz1);
            accr1 = MFMA16(ldsA(sZR, 256, c16, 128 + 1 * 32 + (g4 << 3)), Pt[(91 + wv * 4 + 1) * 64 + lane], accr1);
            accz0 = MFMA16(ldsA(sZR, 256, c16, 2 * 32 + (g4 << 3)), Pt[(75 + wv * 4 + 2) * 64 + lane], accz0);
            accr0 = MFMA16(ldsA(sZR, 256, c16, 128 + 2 * 32 + (g4 << 3)), Pt[(91 + wv * 4 + 2) * 64 + lane], accr0);
            accz1 = MFMA16(ldsA(sZR, 256, c16, 3 * 32 + (g4 << 3)), Pt[(75 + wv * 4 + 3) * 64 + lane], accz1);
            accr1 = MFMA16(ldsA(sZR, 256, c16, 128 + 3 * 32 + (g4 << 3)), Pt[(91 + wv * 4 + 3) * 64 + lane], accr1);
            #pragma unroll
            for (int r = 0; r < 4; ++r) {
                int row = g4 * 4 + r;
                zg[r] = fast_sigmoid(accz0[r] + accz1[r] + b_z2);
                float rv = fast_sigmoid(accr0[r] + accr1[r] + b_r2) * yo[r];
                sRX[row * 128 + SWZ(row, colw)] = (_Float16)rv;
            }
        }
        __syncthreads();

        // ---- G5: H1 = tanh([rg*yode|x] @ Wh1 + bh1) ----
        {
            f16x8 a0 = ldsA(sRX, 128, c16, 0 * 32 + (g4 << 3));
            f16x8 a1 = ldsA(sRX, 128, c16, 1 * 32 + (g4 << 3));
            f16x8 a2 = ldsA(sRX, 128, c16, 2 * 32 + (g4 << 3));
            #pragma unroll
            for (int t = 0; t < 2; ++t) {
                int nt = wv + 4 * t;
                if (nt < 7) {
                    f32x4 z4 = {0.f, 0.f, 0.f, 0.f};
                    f32x4 acc0 = MFMA16(a0, Pt[(107 + nt * 3 + 0) * 64 + lane], z4);
                    f32x4 acc1 = MFMA16(a1, Pt[(107 + nt * 3 + 1) * 64 + lane], z4);
                    acc0 = MFMA16(a2, Pt[(107 + nt * 3 + 2) * 64 + lane], acc0);
                    int col = nt * 16 + c16;
                    #pragma unroll
                    for (int r = 0; r < 4; ++r) {
                        int row = g4 * 4 + r;
                        sH1[row * 128 + SWZ(row, col)] = (_Float16)fast_tanh(acc0[r] + acc1[r] + b_h1[t]);
                    }
                }
            }
        }
        __syncthreads();

        // ---- G6: h = tanh(H1 @ Wh2 + bh2); y = (1-z)*h + z*yode (all regs) ----
        {
            f32x4 z4 = {0.f, 0.f, 0.f, 0.f};
            f32x4 acc0 = z4, acc1 = z4;
            acc0 = MFMA16(ldsA(sH1, 128, c16, 0 * 32 + (g4 << 3)), Bh2[0], acc0);
            acc1 = MFMA16(ldsA(sH1, 128, c16, 1 * 32 + (g4 << 3)), Bh2[1], acc1);
            acc0 = MFMA16(ldsA(sH1, 128, c16, 2 * 32 + (g4 << 3)), Bh2[2], acc0);
            acc1 = MFMA16(ldsA(sH1, 128, c16, 3 * 32 + (g4 << 3)), Bh2[3], acc1);
            #pragma unroll
            for (int r = 0; r < 4; ++r) {
                int row = g4 * 4 + r;
                float h = fast_tanh(acc0[r] + acc1[r] + b_h2);
                y[r] = (1.f - zg[r]) * h + zg[r] * yo[r];
                sYb[row * 64 + SWZ(row, colw)] = (_Float16)y[r];
            }
        }
        __syncthreads();

        xv_cur = xv_next;
    }

    // only rows 0..7 are real trajectories
    if (g4 < 2) {
        #pragma unroll
        for (int r = 0; r < 4; ++r) {
            int row = g4 * 4 + r;
            out[(size_t)(m0 + row) * 64 + colw] = y[r];
        }
    }
}

extern "C" void kernel_launch(void* const* d_in, const int* in_sizes, int n_in,
                              void* d_out, int out_size, void* d_ws, size_t ws_size,
                              hipStream_t stream) {
    const float* data = (const float*)d_in[0];
    const float* ts   = (const float*)d_in[1];
    const float* prior= (const float*)d_in[2];
    const float* Wo1 = (const float*)d_in[3];  const float* bo1 = (const float*)d_in[4];
    const float* Wo2 = (const float*)d_in[5];  const float* bo2 = (const float*)d_in[6];
    const float* Wz1 = (const float*)d_in[7];  const float* bz1 = (const float*)d_in[8];
    const float* Wz2 = (const float*)d_in[9];  const float* bz2 = (const float*)d_in[10];
    const float* Wr1 = (const float*)d_in[11]; const float* br1 = (const float*)d_in[12];
    const float* Wr2 = (const float*)d_in[13]; const float* br2 = (const float*)d_in[14];
    const float* Wh1 = (const float*)d_in[15]; const float* bh1 = (const float*)d_in[16];
    const float* Wh2 = (const float*)d_in[17]; const float* bh2 = (const float*)d_in[18];
    _Float16* P = (_Float16*)d_ws;
    float* out = (float*)d_out;

    hipLaunchKernelGGL(pack_kernel, dim3((144 * 512 + 255) / 256), dim3(256), 0, stream,
                       Wo1, Wo2, Wz1, Wz2, Wr1, Wr2, Wh1, Wh2, P);
    hipLaunchKernelGGL(odernn_kernel, dim3(NTRAJ / MBLK), dim3(256), 0, stream,
                       data, ts, prior, bo1, bo2, bz1, bz2, br1, br2, bh1, bh2, P, out);
}

// Round 7
// 351.105 us; speedup vs baseline: 5.8297x; 2.0298x over previous
//
#include <hip/hip_runtime.h>

#define T_STEPS 100
#define NTRAJ   8192
#define MBLK    32     // trajectories per block: two 16-row tile groups
#define W_TILES 112    // LDS-cached weight tiles (G1,G3,G4,G5)
#define W_BYTES (W_TILES * 1024)
#define TILEBUF 22528  // per-tile activation buffers (bytes)
#define LDS_TOTAL (W_BYTES + 2 * TILEBUF)   // 159744 <= 163840

typedef __attribute__((ext_vector_type(8))) _Float16 f16x8;
typedef __attribute__((ext_vector_type(4))) float    f32x4;

#define MFMA16(a, b, c) __builtin_amdgcn_mfma_f32_16x16x32_f16((a), (b), (c), 0, 0, 0)

// XOR swizzle on element index within a row (2B elems; XOR elem bits 3..5)
#define SWZ(row, col) ((col) ^ (((row) & 7) << 3))

__device__ __forceinline__ float fast_tanh(float x) {
    float e = __expf(2.f * x);
    return 1.f - 2.f * __builtin_amdgcn_rcpf(1.f + e);
}
__device__ __forceinline__ float fast_sigmoid(float x) {
    float e = __expf(-x);
    return __builtin_amdgcn_rcpf(1.f + e);
}

// ---------------------------------------------------------------------------
// Weight packing (unchanged): B-fragment tile order, 144 tiles of 512 f16.
//   [0,14) G1 | [14,30) G2 | [30,75) G3 | [75,107) G4 | [107,128) G5 | [128,144) G6
// ---------------------------------------------------------------------------
__global__ void pack_kernel(const float* __restrict__ Wo1, const float* __restrict__ Wo2,
                            const float* __restrict__ Wz1, const float* __restrict__ Wz2,
                            const float* __restrict__ Wr1, const float* __restrict__ Wr2,
                            const float* __restrict__ Wh1, const float* __restrict__ Wh2,
                            _Float16* __restrict__ P)
{
    int idx = blockIdx.x * 256 + threadIdx.x;
    if (idx >= 144 * 512) return;
    int tile = idx >> 9;
    int r    = idx & 511;
    int lane = r >> 3, j = r & 7;
    int krel = ((lane >> 4) << 3) + j;   // 0..31
    int c16  = lane & 15;
    float val = 0.f;

    if (tile < 14) {                       // ODE L1
        int t = tile, nt = t >> 1, kt = t & 1;
        int k = kt * 32 + krel, n = nt * 16 + c16;
        if (k < 64 && n < 100) val = Wo1[k * 100 + n];
    } else if (tile < 30) {                // ODE L2
        int t = tile - 14, nt = t >> 2, kt = t & 3;
        int k = kt * 32 + krel, n = nt * 16 + c16;
        if (k < 100) val = Wo2[k * 64 + n];
    } else if (tile < 75) {                // ZR L1
        int t = tile - 30, nt = t / 3, kt = t % 3;
        int k = kt * 32 + krel;            // K = 96 exact
        if (nt < 7)      { int n = nt * 16 + c16;        if (n < 100) val = Wz1[k * 100 + n]; }
        else if (nt >= 8){ int n = (nt - 8) * 16 + c16;  if (n < 100) val = Wr1[k * 100 + n]; }
    } else if (tile < 107) {               // ZR L2
        int t = tile - 75, gate = t >> 4, rem = t & 15, nt = rem >> 2, kt = rem & 3;
        int k = kt * 32 + krel, n = nt * 16 + c16;
        const float* W = gate ? Wr2 : Wz2;
        if (k < 100) val = W[k * 64 + n];
    } else if (tile < 128) {               // H L1
        int t = tile - 107, nt = t / 3, kt = t % 3;
        int k = kt * 32 + krel, n = nt * 16 + c16;
        if (n < 100) val = Wh1[k * 100 + n];
    } else {                               // H L2
        int t = tile - 128, nt = t >> 2, kt = t & 3;
        int k = kt * 32 + krel, n = nt * 16 + c16;
        if (k < 100) val = Wh2[k * 64 + n];
    }
    P[idx] = (_Float16)val;
}

__device__ __forceinline__ f16x8 ldsA(const _Float16* buf, int stride, int row, int kcol) {
    return *(const f16x8*)(buf + row * stride + SWZ(row, kcol));
}

// ---------------------------------------------------------------------------
// Main kernel. Block = 32 trajectories = TWO independent 16-row tile groups
// (waves 0-3 -> tile 0, waves 4-7 -> tile 1), 512 threads. Grid = 256 = one
// block per CU. All G1/G3/G4/G5 weight fragments live in LDS (staged once,
// 114.7 KB) -> zero steady-state L2 traffic in the 6-phase critical path.
// G2/G6 fragments stay in registers. Occupancy is register-capped at 2
// waves/SIMD for this family (rounds 2/4/5 evidence) — this design accepts
// that and shortens the per-phase latency instead.
// ---------------------------------------------------------------------------
__global__ __launch_bounds__(512, 2) void odernn_kernel(
    const float* __restrict__ data, const float* __restrict__ ts,
    const float* __restrict__ prior,
    const float* __restrict__ bo1, const float* __restrict__ bo2,
    const float* __restrict__ bz1, const float* __restrict__ bz2,
    const float* __restrict__ br1, const float* __restrict__ br2,
    const float* __restrict__ bh1, const float* __restrict__ bh2,
    const _Float16* __restrict__ P, float* __restrict__ out)
{
    extern __shared__ __align__(16) char smem[];
    _Float16* W = (_Float16*)smem;                 // 112 tiles, linear frag order

    const int tid  = threadIdx.x;
    const int lane = tid & 63;
    const int wv   = tid >> 6;            // 0..7
    const int tg   = wv >> 2;             // tile group 0/1
    const int wq   = wv & 3;              // wave-in-group 0..3
    const int c16  = lane & 15;
    const int g4   = lane >> 4;
    const int m0b  = blockIdx.x * MBLK;   // block's first trajectory
    const int m0   = m0b + tg * 16;       // this tile group's first trajectory
    const int colw = wq * 16 + c16;       // this lane's "own" column
    const f16x8* Pt = (const f16x8*)P;
    const f16x8* Wv = (const f16x8*)W;

    // per-tile activation buffers
    _Float16* base = (_Float16*)(smem + W_BYTES + tg * TILEBUF);
    _Float16* sYb = base;                 // [16][64]  y (f16), G1 A input
    _Float16* sYX = base + 1024;          // [16][128] [yode | x]
    _Float16* sRX = base + 3072;          // [16][128] [rg*yode | x]
    _Float16* sH1 = base + 5120;          // [16][128] hidden (ODE L1 / H L1)
    _Float16* sZR = base + 7168;          // [16][256] [zh(112)+pad | rh(112)+pad]

    // ---- stage all G1/G3/G4/G5 weight tiles into LDS (one time) ----
    {
        f16x8* Wd = (f16x8*)W;
        #pragma unroll
        for (int it = 0; it < 14; ++it) {
            int idx = tid + it * 512;            // [0, 7168)
            int ldst = idx >> 6, l = idx & 63;
            int srct = (ldst < 14) ? ldst : ldst + 16;   // skip G2 range
            Wd[idx] = Pt[srct * 64 + l];
        }
    }

    // ---- preload biases (step-invariant per lane) ----
    float b_o1[2], b_h1[2], b_zr[4];
    {
        int c0 = wq * 16 + c16, c1 = (wq + 4) * 16 + c16;
        b_o1[0] = (c0 < 100) ? bo1[c0] : 0.f;
        b_h1[0] = (c0 < 100) ? bh1[c0] : 0.f;
        b_o1[1] = (wq + 4 < 7 && c1 < 100) ? bo1[c1] : 0.f;
        b_h1[1] = (wq + 4 < 7 && c1 < 100) ? bh1[c1] : 0.f;
        #pragma unroll
        for (int q = 0; q < 4; ++q) {
            int i = wq + 4 * q;
            float v = 0.f;
            if (i < 14) {
                int bt = (i < 7) ? i : i + 1;
                int col = bt * 16 + c16;
                int bc = (i < 7) ? col : col - 128;
                if (bc < 100) v = (i < 7) ? bz1[bc] : br1[bc];
            }
            b_zr[q] = v;
        }
    }
    const float b_o2 = bo2[colw], b_z2 = bz2[colw], b_r2 = br2[colw], b_h2 = bh2[colw];

    // ---- preload B-fragments for the short dependent phases G2/G6 (regs) ----
    f16x8 Bo2[4], Bh2[4];
    #pragma unroll
    for (int kt = 0; kt < 4; ++kt) {
        Bo2[kt] = Pt[(14 + wq * 4 + kt) * 64 + lane];
        Bh2[kt] = Pt[(128 + wq * 4 + kt) * 64 + lane];
    }

    // ---- init: y state in regs, sYb, LDS pads ----
    float y[4];
    #pragma unroll
    for (int r = 0; r < 4; ++r) {
        int row = g4 * 4 + r;
        y[r] = prior[(size_t)(m0 + row) * 64 + colw];
        sYb[row * 64 + SWZ(row, colw)] = (_Float16)y[r];
    }
    {   // sH1 pad cols 112..127, 32 rows total (512 elems, 1/thread)
        int row32 = tid >> 4, col = 112 + (tid & 15);
        int t = row32 >> 4, r16 = row32 & 15;
        _Float16* h1 = (_Float16*)(smem + W_BYTES + t * TILEBUF) + 5120;
        h1[r16 * 128 + SWZ(r16, col)] = (_Float16)0.f;
    }
    for (int i = tid; i < 2 * 16 * 32; i += 512) {   // sZR pads (both tiles)
        int t = i >> 9, rem = i & 511;
        int r16 = rem >> 5, cc = rem & 31;
        int col = (cc < 16) ? (112 + cc) : (224 + cc);
        _Float16* zr = (_Float16*)(smem + W_BYTES + t * TILEBUF) + 7168;
        zr[r16 * 256 + SWZ(r16, col)] = (_Float16)0.f;
    }
    __syncthreads();

    const float t0 = ts[0], t1 = ts[1];

    // x elements owned by this thread: flat {tid, tid+512} of 1024 = 32 rows x 32 cols
    const int xr0 = tid >> 5, xc0 = tid & 31;            // rows 0..15  (tile 0)
    const int xr1 = (tid + 512) >> 5, xc1 = tid & 31;    // rows 16..31 (tile 1)
    const float* xp0 = data + (size_t)(m0b + xr0) * (T_STEPS * 32) + 32 + xc0;
    const float* xp1 = data + (size_t)(m0b + xr1) * (T_STEPS * 32) + 32 + xc1;
    _Float16* yx0 = (_Float16*)(smem + W_BYTES + 0 * TILEBUF);
    _Float16* yx1 = (_Float16*)(smem + W_BYTES + 1 * TILEBUF);
    const int xsw0 = (xr0 & 15) * 128 + SWZ((xr0 & 15), 64 + xc0);
    const int xsw1 = (xr1 & 15) * 128 + SWZ((xr1 & 15), 64 + xc1);
    float xv0 = *xp0, xv1 = *xp1;

    #pragma unroll 1
    for (int s = 0; s < T_STEPS - 1; ++s) {
        const float dt = (s == 0) ? (t1 - t0) : (ts[s - 1] - ts[s]);

        // prefetch next step's x
        xp0 += 32; xp1 += 32;
        float xn0 = (s < T_STEPS - 2) ? *xp0 : 0.f;
        float xn1 = (s < T_STEPS - 2) ? *xp1 : 0.f;

        // ---- G1: H1 = tanh(y @ Wo1 + bo1)  [16x64]@[64x112] ----
        {
            f16x8 a0 = ldsA(sYb, 64, c16, (g4 << 3));
            f16x8 a1 = ldsA(sYb, 64, c16, 32 + (g4 << 3));
            #pragma unroll
            for (int t = 0; t < 2; ++t) {
                int nt = wq + 4 * t;
                if (nt < 7) {
                    f32x4 z4 = {0.f, 0.f, 0.f, 0.f};
                    f32x4 acc0 = MFMA16(a0, Wv[(nt * 2 + 0) * 64 + lane], z4);
                    f32x4 acc1 = MFMA16(a1, Wv[(nt * 2 + 1) * 64 + lane], z4);
                    int col = nt * 16 + c16;
                    #pragma unroll
                    for (int r = 0; r < 4; ++r) {
                        int row = g4 * 4 + r;
                        sH1[row * 128 + SWZ(row, col)] = (_Float16)fast_tanh(acc0[r] + acc1[r] + b_o1[t]);
                    }
                }
            }
        }
        // ---- stage current x into both concat buffers (2 elems/thread) ----
        {
            _Float16 xh0 = (_Float16)xv0, xh1 = (_Float16)xv1;
            yx0[1024 + xsw0] = xh0; yx0[3072 + xsw0] = xh0;   // sYX/sRX tile 0
            yx1[1024 + xsw1] = xh1; yx1[3072 + xsw1] = xh1;   // sYX/sRX tile 1
        }
        __syncthreads();

        // ---- G2: yode = y + dt*(H1 @ Wo2 + bo2); yode in regs ----
        float yo[4];
        {
            f32x4 z4 = {0.f, 0.f, 0.f, 0.f};
            f32x4 acc0 = z4, acc1 = z4;
            acc0 = MFMA16(ldsA(sH1, 128, c16, 0 * 32 + (g4 << 3)), Bo2[0], acc0);
            acc1 = MFMA16(ldsA(sH1, 128, c16, 1 * 32 + (g4 << 3)), Bo2[1], acc1);
            acc0 = MFMA16(ldsA(sH1, 128, c16, 2 * 32 + (g4 << 3)), Bo2[2], acc0);
            acc1 = MFMA16(ldsA(sH1, 128, c16, 3 * 32 + (g4 << 3)), Bo2[3], acc1);
            #pragma unroll
            for (int r = 0; r < 4; ++r) {
                int row = g4 * 4 + r;
                yo[r] = y[r] + dt * (acc0[r] + acc1[r] + b_o2);
                sYX[row * 128 + SWZ(row, colw)] = (_Float16)yo[r];
            }
        }
        __syncthreads();

        // ---- G3: zr-hidden = tanh([yode|x] @ W{z,r}1 + b)  [16x96]@[96x224] ----
        {
            f16x8 a0 = ldsA(sYX, 128, c16, 0 * 32 + (g4 << 3));
            f16x8 a1 = ldsA(sYX, 128, c16, 1 * 32 + (g4 << 3));
            f16x8 a2 = ldsA(sYX, 128, c16, 2 * 32 + (g4 << 3));
            #pragma unroll
            for (int q = 0; q < 4; ++q) {
                int i = wq + 4 * q;
                if (i < 14) {
                    int bt = (i < 7) ? i : i + 1;
                    f32x4 z4 = {0.f, 0.f, 0.f, 0.f};
                    f32x4 acc0 = MFMA16(a0, Wv[(14 + bt * 3 + 0) * 64 + lane], z4);
                    f32x4 acc1 = MFMA16(a1, Wv[(14 + bt * 3 + 1) * 64 + lane], z4);
                    acc0 = MFMA16(a2, Wv[(14 + bt * 3 + 2) * 64 + lane], acc0);
                    int col = bt * 16 + c16;
                    #pragma unroll
                    for (int r = 0; r < 4; ++r) {
                        int row = g4 * 4 + r;
                        sZR[row * 256 + SWZ(row, col)] = (_Float16)fast_tanh(acc0[r] + acc1[r] + b_zr[q]);
                    }
                }
            }
        }
        __syncthreads();

        // ---- G4: wave owns tile nt=wq for BOTH gates; zg regs, rg*yode->sRX ----
        float zg[4];
        {
            f32x4 z4 = {0.f, 0.f, 0.f, 0.f};
            f32x4 accz0 = z4, accz1 = z4, accr0 = z4, accr1 = z4;
            accz0 = MFMA16(ldsA(sZR, 256, c16, 0 * 32 + (g4 << 3)), Wv[(59 + wq * 4 + 0) * 64 + lane], accz0);
            accr0 = MFMA16(ldsA(sZR, 256, c16, 128 + 0 * 32 + (g4 << 3)), Wv[(75 + wq * 4 + 0) * 64 + lane], accr0);
            accz1 = MFMA16(ldsA(sZR, 256, c16, 1 * 32 + (g4 << 3)), Wv[(59 + wq * 4 + 1) * 64 + lane], accz1);
            accr1 = MFMA16(ldsA(sZR, 256, c16, 128 + 1 * 32 + (g4 << 3)), Wv[(75 + wq * 4 + 1) * 64 + lane], accr1);
            accz0 = MFMA16(ldsA(sZR, 256, c16, 2 * 32 + (g4 << 3)), Wv[(59 + wq * 4 + 2) * 64 + lane], accz0);
            accr0 = MFMA16(ldsA(sZR, 256, c16, 128 + 2 * 32 + (g4 << 3)), Wv[(75 + wq * 4 + 2) * 64 + lane], accr0);
            accz1 = MFMA16(ldsA(sZR, 256, c16, 3 * 32 + (g4 << 3)), Wv[(59 + wq * 4 + 3) * 64 + lane], accz1);
            accr1 = MFMA16(ldsA(sZR, 256, c16, 128 + 3 * 32 + (g4 << 3)), Wv[(75 + wq * 4 + 3) * 64 + lane], accr1);
            #pragma unroll
            for (int r = 0; r < 4; ++r) {
                int row = g4 * 4 + r;
                zg[r] = fast_sigmoid(accz0[r] + accz1[r] + b_z2);
                float rv = fast_sigmoid(accr0[r] + accr1[r] + b_r2) * yo[r];
                sRX[row * 128 + SWZ(row, colw)] = (_Float16)rv;
            }
        }
        __syncthreads();

        // ---- G5: H1 = tanh([rg*yode|x] @ Wh1 + bh1) ----
        {
            f16x8 a0 = ldsA(sRX, 128, c16, 0 * 32 + (g4 << 3));
            f16x8 a1 = ldsA(sRX, 128, c16, 1 * 32 + (g4 << 3));
            f16x8 a2 = ldsA(sRX, 128, c16, 2 * 32 + (g4 << 3));
            #pragma unroll
            for (int t = 0; t < 2; ++t) {
                int nt = wq + 4 * t;
                if (nt < 7) {
                    f32x4 z4 = {0.f, 0.f, 0.f, 0.f};
                    f32x4 acc0 = MFMA16(a0, Wv[(91 + nt * 3 + 0) * 64 + lane], z4);
                    f32x4 acc1 = MFMA16(a1, Wv[(91 + nt * 3 + 1) * 64 + lane], z4);
                    acc0 = MFMA16(a2, Wv[(91 + nt * 3 + 2) * 64 + lane], acc0);
                    int col = nt * 16 + c16;
                    #pragma unroll
                    for (int r = 0; r < 4; ++r) {
                        int row = g4 * 4 + r;
                        sH1[row * 128 + SWZ(row, col)] = (_Float16)fast_tanh(acc0[r] + acc1[r] + b_h1[t]);
                    }
                }
            }
        }
        __syncthreads();

        // ---- G6: h = tanh(H1 @ Wh2 + bh2); y = (1-z)*h + z*yode (all regs) ----
        {
            f32x4 z4 = {0.f, 0.f, 0.f, 0.f};
            f32x4 acc0 = z4, acc1 = z4;
            acc0 = MFMA16(ldsA(sH1, 128, c16, 0 * 32 + (g4 << 3)), Bh2[0], acc0);
            acc1 = MFMA16(ldsA(sH1, 128, c16, 1 * 32 + (g4 << 3)), Bh2[1], acc1);
            acc0 = MFMA16(ldsA(sH1, 128, c16, 2 * 32 + (g4 << 3)), Bh2[2], acc0);
            acc1 = MFMA16(ldsA(sH1, 128, c16, 3 * 32 + (g4 << 3)), Bh2[3], acc1);
            #pragma unroll
            for (int r = 0; r < 4; ++r) {
                int row = g4 * 4 + r;
                float h = fast_tanh(acc0[r] + acc1[r] + b_h2);
                y[r] = (1.f - zg[r]) * h + zg[r] * yo[r];
                sYb[row * 64 + SWZ(row, colw)] = (_Float16)y[r];
            }
        }
        __syncthreads();

        xv0 = xn0; xv1 = xn1;
    }

    #pragma unroll
    for (int r = 0; r < 4; ++r) {
        int row = g4 * 4 + r;
        out[(size_t)(m0 + row) * 64 + colw] = y[r];
    }
}

extern "C" void kernel_launch(void* const* d_in, const int* in_sizes, int n_in,
                              void* d_out, int out_size, void* d_ws, size_t ws_size,
                              hipStream_t stream) {
    const float* data = (const float*)d_in[0];
    const float* ts   = (const float*)d_in[1];
    const float* prior= (const float*)d_in[2];
    const float* Wo1 = (const float*)d_in[3];  const float* bo1 = (const float*)d_in[4];
    const float* Wo2 = (const float*)d_in[5];  const float* bo2 = (const float*)d_in[6];
    const float* Wz1 = (const float*)d_in[7];  const float* bz1 = (const float*)d_in[8];
    const float* Wz2 = (const float*)d_in[9];  const float* bz2 = (const float*)d_in[10];
    const float* Wr1 = (const float*)d_in[11]; const float* br1 = (const float*)d_in[12];
    const float* Wr2 = (const float*)d_in[13]; const float* br2 = (const float*)d_in[14];
    const float* Wh1 = (const float*)d_in[15]; const float* bh1 = (const float*)d_in[16];
    const float* Wh2 = (const float*)d_in[17]; const float* bh2 = (const float*)d_in[18];
    _Float16* P = (_Float16*)d_ws;
    float* out = (float*)d_out;

    // opt-in to >64KB dynamic LDS (immediate API, not captured; deterministic)
    static int lds_set = 0;
    hipFuncSetAttribute((const void*)odernn_kernel,
                        hipFuncAttributeMaxDynamicSharedMemorySize, LDS_TOTAL);
    (void)lds_set;

    hipLaunchKernelGGL(pack_kernel, dim3((144 * 512 + 255) / 256), dim3(256), 0, stream,
                       Wo1, Wo2, Wz1, Wz2, Wr1, Wr2, Wh1, Wh2, P);
    hipLaunchKernelGGL(odernn_kernel, dim3(NTRAJ / MBLK), dim3(512), LDS_TOTAL, stream,
                       data, ts, prior, bo1, bo2, bz1, bz2, br1, br2, bh1, bh2, P, out);
}